// Round 7
// baseline (98.935 us; speedup 1.0000x reference)
//
#include <hip/hip_runtime.h>
#include <hip/hip_bf16.h>
#include <stdint.h>

#define N_TOKENS    16384
#define MODEL_DIM   2048
#define NUM_EXPERTS 16
#define CAPACITY    2048
#define NBLK        256    // token blocks of 64
// d_out is FLOAT32. Element layout: [0]=l_aux, [1..32769)=weights[N][2],
// [32769..65537)=indices[E*CAP], [65537..98305)=expert_ids[E*CAP]
#define W_OFF       1
#define IDX_OFF     (1 + 2 * N_TOKENS)                  // 32769
#define EID_OFF     (IDX_OFF + NUM_EXPERTS * CAPACITY)  // 65537

// Scratch inside d_out's expert_ids region (131 KB available, 57 KB used);
// clobbered only by the FINAL kernel k_eid. Same-stream serialization.
#define SCR_BYTE  (4 * EID_OFF)
#define SC_E01    0        // uint8  [16384]: e1 | (e2<<4)
#define SC_CNT    16384    // uint16 [16][256] routed counts per block
#define SC_START  24576    // uint16 [16][256] exclusive prefix
#define SC_ME     32768    // float  [256][16] gate sums per block
#define SC_CE2    49152    // uint16 [16][256] argmax counts per block

// DPP butterfly add (intra-16-lane): xor1=0xB1, xor2=0x4E,
// xor7=ROW_HALF_MIRROR=0x141, xor15=ROW_MIRROR=0x140.
#define DPP_ADD(v, ctrl)                                                      \
  (v) += __int_as_float(__builtin_amdgcn_update_dpp(                          \
      0, __float_as_int(v), (ctrl), 0xF, 0xF, true))

__device__ __forceinline__ float dot4(float4 a, float4 b) {
  return a.x * b.x + a.y * b.y + a.z * b.z + a.w * b.w;
}

// ============ K1: fused GEMV + softmax + top2 + counts + me/ce ============
// 256 blocks x 1024 thr (16 waves = 4/SIMD, 50% occ). Block b: tokens
// [b*64, b*64+64). Wave wv owns tokens wv*4..wv*4+3 (T=4). Lane l owns
// k-offsets {j*256 + l*4 + 0..3}. x: coalesced 1KB loads, read once,
// prefetch-next-j. wg: staged per-j in LDS (double-buffered, conflict-free
// b128), wave wv stages expert row wv. One barrier per j.
__global__ __launch_bounds__(1024, 4) void k_gate(
    const float* __restrict__ x, const float* __restrict__ wg,
    float* __restrict__ out, uint8_t* __restrict__ scr)
{
  __shared__ float swbuf[2][NUM_EXPERTS][256];   // 32 KB w double-buffer
  __shared__ float red[16 * 64 * 4];             // 16 KB [val(e4,g)][tok][4]
  const int tid = threadIdx.x;
  const int b = blockIdx.x;
  const int l = tid & 63;
  const int wv = tid >> 6;             // 0..15 (== expert row it stages)
  const int kb = l * 4;
  const float* xbase = x + ((size_t)(b * 64 + wv * 4)) * MODEL_DIM + kb;

  // stage j=0 (wave wv loads expert wv's 256-chunk: 1KB coalesced)
  *reinterpret_cast<float4*>(&swbuf[0][wv][kb]) =
      *reinterpret_cast<const float4*>(wg + wv * MODEL_DIM + kb);
  // prefetch x j=0
  float4 xv[4], xn[4];
#pragma unroll
  for (int t = 0; t < 4; ++t)
    xv[t] = *reinterpret_cast<const float4*>(xbase + (size_t)t * MODEL_DIM);
  __syncthreads();

  float4 acc[4][4];
#pragma unroll
  for (int t = 0; t < 4; ++t)
#pragma unroll
    for (int e4 = 0; e4 < 4; ++e4) acc[t][e4] = make_float4(0.f, 0.f, 0.f, 0.f);

  for (int j = 0; j < 8; ++j) {
    float4 wn;
    if (j < 7) {   // prefetch next chunk (x and this wave's expert row)
      const float* xj = xbase + (j + 1) * 256;
#pragma unroll
      for (int t = 0; t < 4; ++t)
        xn[t] = *reinterpret_cast<const float4*>(xj + (size_t)t * MODEL_DIM);
      wn = *reinterpret_cast<const float4*>(wg + wv * MODEL_DIM + (j + 1) * 256 + kb);
    }
    const int jb = j & 1;
#pragma unroll
    for (int q = 0; q < 4; ++q) {      // experts in quarters (VGPR bound)
      float4 w0 = *reinterpret_cast<const float4*>(&swbuf[jb][q * 4 + 0][kb]);
      float4 w1 = *reinterpret_cast<const float4*>(&swbuf[jb][q * 4 + 1][kb]);
      float4 w2 = *reinterpret_cast<const float4*>(&swbuf[jb][q * 4 + 2][kb]);
      float4 w3 = *reinterpret_cast<const float4*>(&swbuf[jb][q * 4 + 3][kb]);
#pragma unroll
      for (int t = 0; t < 4; ++t) {
        acc[t][q].x += dot4(xv[t], w0);
        acc[t][q].y += dot4(xv[t], w1);
        acc[t][q].z += dot4(xv[t], w2);
        acc[t][q].w += dot4(xv[t], w3);
      }
    }
    if (j < 7) {
      *reinterpret_cast<float4*>(&swbuf[jb ^ 1][wv][kb]) = wn;
#pragma unroll
      for (int t = 0; t < 4; ++t) xv[t] = xn[t];
    }
    __syncthreads();
  }

  // intra-16-lane butterfly sum via DPP (VALU pipe), masks {1,2,7,15}
#pragma unroll
  for (int t = 0; t < 4; ++t) {
#pragma unroll
    for (int e4 = 0; e4 < 4; ++e4) {
      DPP_ADD(acc[t][e4].x, 0xB1);  DPP_ADD(acc[t][e4].x, 0x4E);
      DPP_ADD(acc[t][e4].x, 0x141); DPP_ADD(acc[t][e4].x, 0x140);
      DPP_ADD(acc[t][e4].y, 0xB1);  DPP_ADD(acc[t][e4].y, 0x4E);
      DPP_ADD(acc[t][e4].y, 0x141); DPP_ADD(acc[t][e4].y, 0x140);
      DPP_ADD(acc[t][e4].z, 0xB1);  DPP_ADD(acc[t][e4].z, 0x4E);
      DPP_ADD(acc[t][e4].z, 0x141); DPP_ADD(acc[t][e4].z, 0x140);
      DPP_ADD(acc[t][e4].w, 0xB1);  DPP_ADD(acc[t][e4].w, 0x4E);
      DPP_ADD(acc[t][e4].w, 0x141); DPP_ADD(acc[t][e4].w, 0x140);
    }
  }

  // leaders (l%16==0, group g=l>>4) write partials: red[(e4*4+g)][tok] f4
  const int g = l >> 4;
  if ((l & 15) == 0) {
#pragma unroll
    for (int t = 0; t < 4; ++t)
#pragma unroll
      for (int e4 = 0; e4 < 4; ++e4)
        *reinterpret_cast<float4*>(&red[((e4 * 4 + g) * 64 + wv * 4 + t) * 4]) = acc[t][e4];
  }
  __syncthreads();

  if (tid < 64) {   // wave 0: lane = token within block
    const int t = b * 64 + tid;
    float logit[NUM_EXPERTS];
#pragma unroll
    for (int e4 = 0; e4 < 4; ++e4) {
      float4 s0 = *reinterpret_cast<const float4*>(&red[((e4 * 4 + 0) * 64 + tid) * 4]);
      float4 s1 = *reinterpret_cast<const float4*>(&red[((e4 * 4 + 1) * 64 + tid) * 4]);
      float4 s2 = *reinterpret_cast<const float4*>(&red[((e4 * 4 + 2) * 64 + tid) * 4]);
      float4 s3 = *reinterpret_cast<const float4*>(&red[((e4 * 4 + 3) * 64 + tid) * 4]);
      logit[e4 * 4 + 0] = (s0.x + s1.x) + (s2.x + s3.x);
      logit[e4 * 4 + 1] = (s0.y + s1.y) + (s2.y + s3.y);
      logit[e4 * 4 + 2] = (s0.z + s1.z) + (s2.z + s3.z);
      logit[e4 * 4 + 3] = (s0.w + s1.w) + (s2.w + s3.w);
    }

    float m = logit[0];
#pragma unroll
    for (int e = 1; e < NUM_EXPERTS; e++) m = fmaxf(m, logit[e]);
    float gg[NUM_EXPERTS]; float z = 0.f;
#pragma unroll
    for (int e = 0; e < NUM_EXPERTS; e++) { gg[e] = expf(logit[e] - m); z += gg[e]; }
    float inv = 1.f / z;
#pragma unroll
    for (int e = 0; e < NUM_EXPERTS; e++) gg[e] *= inv;

    // top-2, ties -> lower index (matches lax.top_k / argmax)
    float v1 = gg[0], v2 = -1.f; int e1 = 0, e2 = 0;
#pragma unroll
    for (int e = 1; e < NUM_EXPERTS; e++) {
      if (gg[e] > v1) { v2 = v1; e2 = e1; v1 = gg[e]; e1 = e; }
      else if (gg[e] > v2) { v2 = gg[e]; e2 = e; }
    }
    out[W_OFF + 2 * t]     = v1;
    out[W_OFF + 2 * t + 1] = v2;
    scr[SC_E01 + t] = (uint8_t)(e1 | (e2 << 4));

    // per-block routed counts + argmax counts (token order preserved)
    int mycount = 0, myce = 0;
    for (int e = 0; e < NUM_EXPERTS; e++) {
      unsigned long long m1 = __ballot(e1 == e);
      unsigned long long m2 = __ballot(e2 == e);
      if (tid == e) { mycount = __popcll(m1 | m2); myce = __popcll(m1); }
    }
    if (tid < NUM_EXPERTS) {
      reinterpret_cast<uint16_t*>(scr + SC_CNT)[tid * NBLK + b] = (uint16_t)mycount;
      reinterpret_cast<uint16_t*>(scr + SC_CE2)[tid * NBLK + b] = (uint16_t)myce;
    }

    // me partial: butterfly over the 64 tokens
#pragma unroll
    for (int e = 0; e < NUM_EXPERTS; e++) {
#pragma unroll
      for (int off = 1; off < 64; off <<= 1) gg[e] += __shfl_xor(gg[e], off, 64);
    }
    if (tid == 0) {
      float* mp = reinterpret_cast<float*>(scr + SC_ME);
#pragma unroll
      for (int e = 0; e < NUM_EXPERTS; e++) mp[b * NUM_EXPERTS + e] = gg[e];
    }
  }
}

// ============ K2: prefix scan + l_aux (fused, 1 block) ============
__global__ __launch_bounds__(256) void k_finish(
    uint8_t* __restrict__ scr, float* __restrict__ out) {
  const uint16_t* counts = reinterpret_cast<const uint16_t*>(scr + SC_CNT);
  uint16_t* starts = reinterpret_cast<uint16_t*>(scr + SC_START);
  __shared__ int gs[NUM_EXPERTS][16];
  __shared__ int gstart[NUM_EXPERTS][17];
  const int tid = threadIdx.x;
  const int e = tid >> 4, grp = tid & 15;
  int s = 0;
  for (int c = grp * 16; c < grp * 16 + 16; c++) s += counts[e * NBLK + c];
  gs[e][grp] = s;
  __syncthreads();
  if (tid < NUM_EXPERTS) {
    int run = 0;
    for (int g2 = 0; g2 < 16; g2++) { gstart[tid][g2] = run; run += gs[tid][g2]; }
  }
  __syncthreads();
  int run = gstart[e][grp];
  for (int c = grp * 16; c < grp * 16 + 16; c++) {
    starts[e * NBLK + c] = (uint16_t)run;
    run += counts[e * NBLK + c];
  }
  // l_aux (wave 0)
  if (tid < 64) {
    float prod = 0.f;
    if (tid < NUM_EXPERTS) {
      const float* mepart = reinterpret_cast<const float*>(scr + SC_ME);
      const uint16_t* ce2 = reinterpret_cast<const uint16_t*>(scr + SC_CE2);
      float ssum = 0.f; int ce = 0;
      for (int b2 = 0; b2 < NBLK; b2++) {
        ssum += mepart[b2 * NUM_EXPERTS + tid];
        ce += ce2[tid * NBLK + b2];
      }
      prod = (ssum * (1.0f / N_TOKENS)) * ((float)ce * (1.0f / N_TOKENS));
    }
#pragma unroll
    for (int off = 32; off > 0; off >>= 1) prod += __shfl_xor(prod, off, 64);
    if (tid == 0) out[0] = prod * (float)NUM_EXPERTS;
  }
}

// ============ K3: scatter token ids into capacity table ============
__global__ __launch_bounds__(64) void k_scatter(
    const uint8_t* __restrict__ scr, float* __restrict__ out) {
  const uint16_t* starts = reinterpret_cast<const uint16_t*>(scr + SC_START);
  const int c = blockIdx.x;
  const int lane = threadIdx.x;
  const int t = c * 64 + lane;
  const int v = scr[SC_E01 + t];
  const int e1 = v & 15, e2 = v >> 4;
  const unsigned long long below = (1ull << lane) - 1ull;
  int p1 = CAPACITY, p2 = CAPACITY;
  for (int e = 0; e < NUM_EXPERTS; e++) {
    unsigned long long m = __ballot(e1 == e) | __ballot(e2 == e);
    int r = __popcll(m & below);
    int sbase = (int)starts[e * NBLK + c];
    if (e1 == e) p1 = sbase + r;
    if (e2 == e) p2 = sbase + r;
  }
  float tf = (float)t;   // exact in fp32
  if ((unsigned)p1 < (unsigned)CAPACITY) out[IDX_OFF + e1 * CAPACITY + p1] = tf;
  if ((unsigned)p2 < (unsigned)CAPACITY) out[IDX_OFF + e2 * CAPACITY + p2] = tf;
}

// ============ K4: fill -1 in empty index slots ============
__global__ __launch_bounds__(256) void k_fill_idx(
    const uint8_t* __restrict__ scr, float* __restrict__ out) {
  const uint16_t* counts = reinterpret_cast<const uint16_t*>(scr + SC_CNT);
  const uint16_t* starts = reinterpret_cast<const uint16_t*>(scr + SC_START);
  const int i = blockIdx.x * 256 + threadIdx.x;   // 0..32767
  const int e = i >> 11;
  const int p = i & (CAPACITY - 1);
  const int tot = (int)starts[e * NBLK + NBLK - 1] + (int)counts[e * NBLK + NBLK - 1];
  if (p >= tot) out[IDX_OFF + i] = -1.0f;
}

// ============ K5 (LAST — clobbers scratch): expert_ids ============
__global__ __launch_bounds__(256) void k_eid(float* __restrict__ out) {
  const int i = blockIdx.x * 256 + threadIdx.x;   // 0..32767
  out[EID_OFF + i] = (float)(i >> 11);
}

extern "C" void kernel_launch(void* const* d_in, const int* in_sizes, int n_in,
                              void* d_out, int out_size, void* d_ws, size_t ws_size,
                              hipStream_t stream) {
  const float* x  = (const float*)d_in[0];
  const float* wg = (const float*)d_in[1];
  float* out = (float*)d_out;
  uint8_t* scr = (uint8_t*)d_out + SCR_BYTE;
  (void)d_ws; (void)ws_size;

  k_gate<<<NBLK, 1024, 0, stream>>>(x, wg, out, scr);
  k_finish<<<1, 256, 0, stream>>>(scr, out);
  k_scatter<<<NBLK, 64, 0, stream>>>(scr, out);
  k_fill_idx<<<128, 256, 0, stream>>>(scr, out);
  k_eid<<<128, 256, 0, stream>>>(out);
}

// Round 8
// 80.728 us; speedup vs baseline: 1.2255x; 1.2255x over previous
//
#include <hip/hip_runtime.h>
#include <hip/hip_bf16.h>
#include <stdint.h>

#define N_TOKENS    16384
#define MODEL_DIM   2048
#define NUM_EXPERTS 16
#define CAPACITY    2048
#define NBLK        256    // 64-token chunks for routing/ballot
#define GBLK        1024   // gemv blocks (16 tokens each)
// d_out is FLOAT32. Element layout: [0]=l_aux, [1..32769)=weights[N][2],
// [32769..65537)=indices[E*CAP], [65537..98305)=expert_ids[E*CAP]
#define W_OFF       1
#define IDX_OFF     (1 + 2 * N_TOKENS)                  // 32769
#define EID_OFF     (IDX_OFF + NUM_EXPERTS * CAPACITY)  // 65537

// Scratch inside d_out's expert_ids region (131072 B available, 106496 used);
// clobbered only by the FINAL kernel k_eid. Same-stream serialization.
#define SCR_BYTE  (4 * EID_OFF)
#define SC_E01    0        // uint8  [16384]: e1 | (e2<<4)
#define SC_ME     16384    // float  [1024][16] gate sums per gemv block
#define SC_CNT    81920    // uint16 [16][256] routed counts per 64-chunk
#define SC_START  90112    // uint16 [16][256] exclusive prefix
#define SC_CE2    98304    // uint16 [16][256] argmax counts per 64-chunk

// DPP butterfly add (intra-16-lane): xor1=0xB1, xor2=0x4E,
// xor7=ROW_HALF_MIRROR=0x141, xor15=ROW_MIRROR=0x140.
#define DPP_ADD(v, ctrl)                                                      \
  (v) += __int_as_float(__builtin_amdgcn_update_dpp(                          \
      0, __float_as_int(v), (ctrl), 0xF, 0xF, true))

__device__ __forceinline__ float dot4(float4 a, float4 b) {
  return a.x * b.x + a.y * b.y + a.z * b.z + a.w * b.w;
}

// ============ K1: GEMV logits + softmax + top2 + weights + me ============
// 1024 blocks x 256 thr (4 waves; 4 blocks/CU -> 4 waves/SIMD, VGPR cap 128).
// Block b: tokens [b*16, b*16+16). Wave wv: tokens b*16+wv*4..+3 (T=4).
// Lane l: k-offsets {j*256 + l*4 + 0..3}, j=0..7. x coalesced (1KB/load-inst),
// read once, next-j prefetched. wg direct from global (L1-hot 16KB/j slab).
__global__ __launch_bounds__(256, 4) void k_logits(
    const float* __restrict__ x, const float* __restrict__ wg,
    float* __restrict__ out, uint8_t* __restrict__ scr)
{
  __shared__ float4 red[16 * 17];      // [tok16][q*4+g], pad 17 -> no conflicts
  const int tid = threadIdx.x;
  const int b = blockIdx.x;
  const int l = tid & 63;
  const int wv = tid >> 6;
  const int kb = l * 4;
  const float* xbase = x + ((size_t)(b * 16 + wv * 4)) * MODEL_DIM + kb;

  float4 acc[4][4];
#pragma unroll
  for (int t = 0; t < 4; ++t)
#pragma unroll
    for (int q = 0; q < 4; ++q) acc[t][q] = make_float4(0.f, 0.f, 0.f, 0.f);

  float4 xv[4];
#pragma unroll
  for (int t = 0; t < 4; ++t)
    xv[t] = *reinterpret_cast<const float4*>(xbase + (size_t)t * MODEL_DIM);

  for (int j = 0; j < 8; ++j) {
    float4 xn[4];
    if (j < 7) {
      const float* xj = xbase + (j + 1) * 256;
#pragma unroll
      for (int t = 0; t < 4; ++t)
        xn[t] = *reinterpret_cast<const float4*>(xj + (size_t)t * MODEL_DIM);
    }
    const float* wj = wg + j * 256 + kb;
#pragma unroll
    for (int q = 0; q < 4; ++q) {
      float4 w0 = *reinterpret_cast<const float4*>(wj + (q * 4 + 0) * MODEL_DIM);
      float4 w1 = *reinterpret_cast<const float4*>(wj + (q * 4 + 1) * MODEL_DIM);
      float4 w2 = *reinterpret_cast<const float4*>(wj + (q * 4 + 2) * MODEL_DIM);
      float4 w3 = *reinterpret_cast<const float4*>(wj + (q * 4 + 3) * MODEL_DIM);
#pragma unroll
      for (int t = 0; t < 4; ++t) {
        acc[t][q].x += dot4(xv[t], w0);
        acc[t][q].y += dot4(xv[t], w1);
        acc[t][q].z += dot4(xv[t], w2);
        acc[t][q].w += dot4(xv[t], w3);
      }
    }
    if (j < 7) {
#pragma unroll
      for (int t = 0; t < 4; ++t) xv[t] = xn[t];
    }
  }

  // intra-16-lane butterfly sum via DPP (VALU pipe), masks {1,2,7,15}
#pragma unroll
  for (int t = 0; t < 4; ++t) {
#pragma unroll
    for (int q = 0; q < 4; ++q) {
      DPP_ADD(acc[t][q].x, 0xB1);  DPP_ADD(acc[t][q].x, 0x4E);
      DPP_ADD(acc[t][q].x, 0x141); DPP_ADD(acc[t][q].x, 0x140);
      DPP_ADD(acc[t][q].y, 0xB1);  DPP_ADD(acc[t][q].y, 0x4E);
      DPP_ADD(acc[t][q].y, 0x141); DPP_ADD(acc[t][q].y, 0x140);
      DPP_ADD(acc[t][q].z, 0xB1);  DPP_ADD(acc[t][q].z, 0x4E);
      DPP_ADD(acc[t][q].z, 0x141); DPP_ADD(acc[t][q].z, 0x140);
      DPP_ADD(acc[t][q].w, 0xB1);  DPP_ADD(acc[t][q].w, 0x4E);
      DPP_ADD(acc[t][q].w, 0x141); DPP_ADD(acc[t][q].w, 0x140);
    }
  }

  // group leaders write partials: red[tok_local*17 + q*4 + g]
  const int g = l >> 4;
  if ((l & 15) == 0) {
#pragma unroll
    for (int t = 0; t < 4; ++t)
#pragma unroll
      for (int q = 0; q < 4; ++q)
        red[(wv * 4 + t) * 17 + q * 4 + g] = acc[t][q];
  }
  __syncthreads();

  if (tid < 16) {   // lane = token within block
    const int t = b * 16 + tid;
    float logit[NUM_EXPERTS];
#pragma unroll
    for (int q = 0; q < 4; ++q) {
      float4 s0 = red[tid * 17 + q * 4 + 0];
      float4 s1 = red[tid * 17 + q * 4 + 1];
      float4 s2 = red[tid * 17 + q * 4 + 2];
      float4 s3 = red[tid * 17 + q * 4 + 3];
      logit[q * 4 + 0] = (s0.x + s1.x) + (s2.x + s3.x);
      logit[q * 4 + 1] = (s0.y + s1.y) + (s2.y + s3.y);
      logit[q * 4 + 2] = (s0.z + s1.z) + (s2.z + s3.z);
      logit[q * 4 + 3] = (s0.w + s1.w) + (s2.w + s3.w);
    }

    float m = logit[0];
#pragma unroll
    for (int e = 1; e < NUM_EXPERTS; e++) m = fmaxf(m, logit[e]);
    float gg[NUM_EXPERTS]; float z = 0.f;
#pragma unroll
    for (int e = 0; e < NUM_EXPERTS; e++) { gg[e] = expf(logit[e] - m); z += gg[e]; }
    float inv = 1.f / z;
#pragma unroll
    for (int e = 0; e < NUM_EXPERTS; e++) gg[e] *= inv;

    // top-2, ties -> lower index (matches lax.top_k / argmax)
    float v1 = gg[0], v2 = -1.f; int e1 = 0, e2 = 0;
#pragma unroll
    for (int e = 1; e < NUM_EXPERTS; e++) {
      if (gg[e] > v1) { v2 = v1; e2 = e1; v1 = gg[e]; e1 = e; }
      else if (gg[e] > v2) { v2 = gg[e]; e2 = e; }
    }
    out[W_OFF + 2 * t]     = v1;
    out[W_OFF + 2 * t + 1] = v2;
    scr[SC_E01 + t] = (uint8_t)(e1 | (e2 << 4));

    // me partial: reduce gates over the block's 16 tokens (lanes 0..15)
#pragma unroll
    for (int e = 0; e < NUM_EXPERTS; e++) {
      gg[e] += __shfl_xor(gg[e], 1, 64);
      gg[e] += __shfl_xor(gg[e], 2, 64);
      gg[e] += __shfl_xor(gg[e], 4, 64);
      gg[e] += __shfl_xor(gg[e], 8, 64);
    }
    if (tid == 0) {
      float* mp = reinterpret_cast<float*>(scr + SC_ME);
#pragma unroll
      for (int e = 0; e < NUM_EXPERTS; e++) mp[b * NUM_EXPERTS + e] = gg[e];
    }
  }
}

// ============ K2: ballot counts per 64-token chunk (token order) ============
__global__ __launch_bounds__(64) void k_route(
    const uint8_t* __restrict__ scr_ro, uint8_t* __restrict__ scr) {
  const int c = blockIdx.x;
  const int lane = threadIdx.x;
  const int v = scr_ro[SC_E01 + c * 64 + lane];
  const int e1 = v & 15, e2 = v >> 4;
  int mycount = 0, myce = 0;
  for (int e = 0; e < NUM_EXPERTS; e++) {
    unsigned long long m1 = __ballot(e1 == e);
    unsigned long long m2 = __ballot(e2 == e);
    if (lane == e) { mycount = __popcll(m1 | m2); myce = __popcll(m1); }
  }
  if (lane < NUM_EXPERTS) {
    reinterpret_cast<uint16_t*>(scr + SC_CNT)[lane * NBLK + c] = (uint16_t)mycount;
    reinterpret_cast<uint16_t*>(scr + SC_CE2)[lane * NBLK + c] = (uint16_t)myce;
  }
}

// ============ K3: prefix scan + l_aux (1 block) ============
__global__ __launch_bounds__(256) void k_finish(
    uint8_t* __restrict__ scr, float* __restrict__ out) {
  const uint16_t* counts = reinterpret_cast<const uint16_t*>(scr + SC_CNT);
  uint16_t* starts = reinterpret_cast<uint16_t*>(scr + SC_START);
  __shared__ int gs[NUM_EXPERTS][16];
  __shared__ int gstart[NUM_EXPERTS][17];
  __shared__ float sme[NUM_EXPERTS][17];
  __shared__ int sce[NUM_EXPERTS][17];
  const int tid = threadIdx.x;
  const int e = tid >> 4, grp = tid & 15;
  int s = 0;
  for (int c = grp * 16; c < grp * 16 + 16; c++) s += counts[e * NBLK + c];
  gs[e][grp] = s;
  // me / ce partial sums (parallel over 256 threads)
  {
    const float* mepart = reinterpret_cast<const float*>(scr + SC_ME);
    const uint16_t* ce2 = reinterpret_cast<const uint16_t*>(scr + SC_CE2);
    float ms = 0.f;
    for (int k = grp; k < GBLK; k += 16) ms += mepart[k * NUM_EXPERTS + e];
    int cs = 0;
    for (int k = grp; k < NBLK; k += 16) cs += ce2[e * NBLK + k];
    sme[e][grp] = ms; sce[e][grp] = cs;
  }
  __syncthreads();
  if (tid < NUM_EXPERTS) {
    int run = 0;
    for (int g2 = 0; g2 < 16; g2++) { gstart[tid][g2] = run; run += gs[tid][g2]; }
  }
  __syncthreads();
  int run = gstart[e][grp];
  for (int c = grp * 16; c < grp * 16 + 16; c++) {
    starts[e * NBLK + c] = (uint16_t)run;
    run += counts[e * NBLK + c];
  }
  if (tid < NUM_EXPERTS) {
    float ssum = 0.f; int ce = 0;
    for (int g2 = 0; g2 < 16; g2++) { ssum += sme[tid][g2]; ce += sce[tid][g2]; }
    float prod = (ssum * (1.0f / N_TOKENS)) * ((float)ce * (1.0f / N_TOKENS));
    prod += __shfl_xor(prod, 1, 64);
    prod += __shfl_xor(prod, 2, 64);
    prod += __shfl_xor(prod, 4, 64);
    prod += __shfl_xor(prod, 8, 64);
    if (tid == 0) out[0] = prod * (float)NUM_EXPERTS;
  }
}

// ============ K4: scatter token ids into capacity table ============
__global__ __launch_bounds__(64) void k_scatter(
    const uint8_t* __restrict__ scr, float* __restrict__ out) {
  const uint16_t* starts = reinterpret_cast<const uint16_t*>(scr + SC_START);
  const int c = blockIdx.x;
  const int lane = threadIdx.x;
  const int t = c * 64 + lane;
  const int v = scr[SC_E01 + t];
  const int e1 = v & 15, e2 = v >> 4;
  const unsigned long long below = (1ull << lane) - 1ull;
  int p1 = CAPACITY, p2 = CAPACITY;
  for (int e = 0; e < NUM_EXPERTS; e++) {
    unsigned long long m = __ballot(e1 == e) | __ballot(e2 == e);
    int r = __popcll(m & below);
    int sbase = (int)starts[e * NBLK + c];
    if (e1 == e) p1 = sbase + r;
    if (e2 == e) p2 = sbase + r;
  }
  float tf = (float)t;   // exact in fp32
  if ((unsigned)p1 < (unsigned)CAPACITY) out[IDX_OFF + e1 * CAPACITY + p1] = tf;
  if ((unsigned)p2 < (unsigned)CAPACITY) out[IDX_OFF + e2 * CAPACITY + p2] = tf;
}

// ============ K5: fill -1 in empty index slots ============
__global__ __launch_bounds__(256) void k_fill_idx(
    const uint8_t* __restrict__ scr, float* __restrict__ out) {
  const uint16_t* counts = reinterpret_cast<const uint16_t*>(scr + SC_CNT);
  const uint16_t* starts = reinterpret_cast<const uint16_t*>(scr + SC_START);
  const int i = blockIdx.x * 256 + threadIdx.x;   // 0..32767
  const int e = i >> 11;
  const int p = i & (CAPACITY - 1);
  const int tot = (int)starts[e * NBLK + NBLK - 1] + (int)counts[e * NBLK + NBLK - 1];
  if (p >= tot) out[IDX_OFF + i] = -1.0f;
}

// ============ K6 (LAST — clobbers scratch): expert_ids ============
__global__ __launch_bounds__(256) void k_eid(float* __restrict__ out) {
  const int i = blockIdx.x * 256 + threadIdx.x;   // 0..32767
  out[EID_OFF + i] = (float)(i >> 11);
}

extern "C" void kernel_launch(void* const* d_in, const int* in_sizes, int n_in,
                              void* d_out, int out_size, void* d_ws, size_t ws_size,
                              hipStream_t stream) {
  const float* x  = (const float*)d_in[0];
  const float* wg = (const float*)d_in[1];
  float* out = (float*)d_out;
  uint8_t* scr = (uint8_t*)d_out + SCR_BYTE;
  (void)d_ws; (void)ws_size;

  k_logits<<<GBLK, 256, 0, stream>>>(x, wg, out, scr);
  k_route<<<NBLK, 64, 0, stream>>>(scr, scr);
  k_finish<<<1, 256, 0, stream>>>(scr, out);
  k_scatter<<<NBLK, 64, 0, stream>>>(scr, out);
  k_fill_idx<<<128, 256, 0, stream>>>(scr, out);
  k_eid<<<128, 256, 0, stream>>>(out);
}

// Round 9
// 78.124 us; speedup vs baseline: 1.2664x; 1.0333x over previous
//
#include <hip/hip_runtime.h>
#include <hip/hip_bf16.h>
#include <stdint.h>

#define N_TOKENS    16384
#define MODEL_DIM   2048
#define NUM_EXPERTS 16
#define CAPACITY    2048
#define NBLK        256    // 64-token chunks for routing/ballot
#define GBLK        1024   // gemv blocks (16 tokens each)
// d_out is FLOAT32. Element layout: [0]=l_aux, [1..32769)=weights[N][2],
// [32769..65537)=indices[E*CAP], [65537..98305)=expert_ids[E*CAP]
#define W_OFF       1
#define IDX_OFF     (1 + 2 * N_TOKENS)                  // 32769
#define EID_OFF     (IDX_OFF + NUM_EXPERTS * CAPACITY)  // 65537

// Scratch inside d_out's expert_ids region (131072 B available, 106496 used);
// clobbered only by the FINAL kernel k_eid. Same-stream serialization.
#define SCR_BYTE  (4 * EID_OFF)
#define SC_E01    0        // uint8  [16384]: e1 | (e2<<4)
#define SC_ME     16384    // float  [1024][16] gate sums per gemv block
#define SC_CNT    81920    // uint16 [16][256] routed counts per 64-chunk
#define SC_START  90112    // uint16 [16][256] exclusive prefix
#define SC_CE2    98304    // uint16 [16][256] argmax counts per 64-chunk

// DPP butterfly add (intra-16-lane): xor1=0xB1, xor2=0x4E,
// xor7=ROW_HALF_MIRROR=0x141, xor15=ROW_MIRROR=0x140.
#define DPP_ADD(v, ctrl)                                                      \
  (v) += __int_as_float(__builtin_amdgcn_update_dpp(                          \
      0, __float_as_int(v), (ctrl), 0xF, 0xF, true))

__device__ __forceinline__ float dot4(float4 a, float4 b) {
  return a.x * b.x + a.y * b.y + a.z * b.z + a.w * b.w;
}

// ============ K1: GEMV logits + softmax + top2 + weights + me ============
// 1024 blocks x 256 thr. amdgpu_waves_per_eu(4,4) pins the allocator at
// 4 waves/SIMD (128-VGPR budget) -- R8's spill cause was the allocator
// targeting 8 waves/SIMD (64-reg cap) and spilling ~60 regs/thread.
// Block b: tokens [b*16, b*16+16). Wave wv: tokens b*16+wv*4..+3 (T=4).
// Lane l: k-offsets {j*256 + l*4 + 0..3}, j=0..7. x coalesced (1KB/inst),
// read once. wg direct from global (L1-hot 16KB/j slab, reused 4 tok x 4 wv).
__global__ void __launch_bounds__(256)
__attribute__((amdgpu_waves_per_eu(4, 4))) k_logits(
    const float* __restrict__ x, const float* __restrict__ wg,
    float* __restrict__ out, uint8_t* __restrict__ scr)
{
  __shared__ float4 red[16 * 17];      // [tok16][q*4+g], pad 17 -> no conflicts
  const int tid = threadIdx.x;
  const int b = blockIdx.x;
  const int l = tid & 63;
  const int wv = tid >> 6;
  const int kb = l * 4;
  const float* xbase = x + ((size_t)(b * 16 + wv * 4)) * MODEL_DIM + kb;

  float4 acc[4][4];
#pragma unroll
  for (int t = 0; t < 4; ++t)
#pragma unroll
    for (int q = 0; q < 4; ++q) acc[t][q] = make_float4(0.f, 0.f, 0.f, 0.f);

  for (int j = 0; j < 8; ++j) {
    float4 xv[4];
    const float* xj = xbase + j * 256;
#pragma unroll
    for (int t = 0; t < 4; ++t)
      xv[t] = *reinterpret_cast<const float4*>(xj + (size_t)t * MODEL_DIM);
    const float* wj = wg + j * 256 + kb;
#pragma unroll
    for (int q = 0; q < 4; ++q) {
      float4 w0 = *reinterpret_cast<const float4*>(wj + (q * 4 + 0) * MODEL_DIM);
      float4 w1 = *reinterpret_cast<const float4*>(wj + (q * 4 + 1) * MODEL_DIM);
      float4 w2 = *reinterpret_cast<const float4*>(wj + (q * 4 + 2) * MODEL_DIM);
      float4 w3 = *reinterpret_cast<const float4*>(wj + (q * 4 + 3) * MODEL_DIM);
#pragma unroll
      for (int t = 0; t < 4; ++t) {
        acc[t][q].x += dot4(xv[t], w0);
        acc[t][q].y += dot4(xv[t], w1);
        acc[t][q].z += dot4(xv[t], w2);
        acc[t][q].w += dot4(xv[t], w3);
      }
    }
  }

  // intra-16-lane butterfly sum via DPP (VALU pipe), masks {1,2,7,15}
#pragma unroll
  for (int t = 0; t < 4; ++t) {
#pragma unroll
    for (int q = 0; q < 4; ++q) {
      DPP_ADD(acc[t][q].x, 0xB1);  DPP_ADD(acc[t][q].x, 0x4E);
      DPP_ADD(acc[t][q].x, 0x141); DPP_ADD(acc[t][q].x, 0x140);
      DPP_ADD(acc[t][q].y, 0xB1);  DPP_ADD(acc[t][q].y, 0x4E);
      DPP_ADD(acc[t][q].y, 0x141); DPP_ADD(acc[t][q].y, 0x140);
      DPP_ADD(acc[t][q].z, 0xB1);  DPP_ADD(acc[t][q].z, 0x4E);
      DPP_ADD(acc[t][q].z, 0x141); DPP_ADD(acc[t][q].z, 0x140);
      DPP_ADD(acc[t][q].w, 0xB1);  DPP_ADD(acc[t][q].w, 0x4E);
      DPP_ADD(acc[t][q].w, 0x141); DPP_ADD(acc[t][q].w, 0x140);
    }
  }

  // group leaders write partials: red[tok_local*17 + q*4 + g]
  const int g = l >> 4;
  if ((l & 15) == 0) {
#pragma unroll
    for (int t = 0; t < 4; ++t)
#pragma unroll
      for (int q = 0; q < 4; ++q)
        red[(wv * 4 + t) * 17 + q * 4 + g] = acc[t][q];
  }
  __syncthreads();

  if (tid < 16) {   // lane = token within block
    const int t = b * 16 + tid;
    float logit[NUM_EXPERTS];
#pragma unroll
    for (int q = 0; q < 4; ++q) {
      float4 s0 = red[tid * 17 + q * 4 + 0];
      float4 s1 = red[tid * 17 + q * 4 + 1];
      float4 s2 = red[tid * 17 + q * 4 + 2];
      float4 s3 = red[tid * 17 + q * 4 + 3];
      logit[q * 4 + 0] = (s0.x + s1.x) + (s2.x + s3.x);
      logit[q * 4 + 1] = (s0.y + s1.y) + (s2.y + s3.y);
      logit[q * 4 + 2] = (s0.z + s1.z) + (s2.z + s3.z);
      logit[q * 4 + 3] = (s0.w + s1.w) + (s2.w + s3.w);
    }

    float m = logit[0];
#pragma unroll
    for (int e = 1; e < NUM_EXPERTS; e++) m = fmaxf(m, logit[e]);
    float gg[NUM_EXPERTS]; float z = 0.f;
#pragma unroll
    for (int e = 0; e < NUM_EXPERTS; e++) { gg[e] = expf(logit[e] - m); z += gg[e]; }
    float inv = 1.f / z;
#pragma unroll
    for (int e = 0; e < NUM_EXPERTS; e++) gg[e] *= inv;

    // top-2, ties -> lower index (matches lax.top_k / argmax)
    float v1 = gg[0], v2 = -1.f; int e1 = 0, e2 = 0;
#pragma unroll
    for (int e = 1; e < NUM_EXPERTS; e++) {
      if (gg[e] > v1) { v2 = v1; e2 = e1; v1 = gg[e]; e1 = e; }
      else if (gg[e] > v2) { v2 = gg[e]; e2 = e; }
    }
    out[W_OFF + 2 * t]     = v1;
    out[W_OFF + 2 * t + 1] = v2;
    scr[SC_E01 + t] = (uint8_t)(e1 | (e2 << 4));

    // me partial: reduce gates over the block's 16 tokens (lanes 0..15)
#pragma unroll
    for (int e = 0; e < NUM_EXPERTS; e++) {
      gg[e] += __shfl_xor(gg[e], 1, 64);
      gg[e] += __shfl_xor(gg[e], 2, 64);
      gg[e] += __shfl_xor(gg[e], 4, 64);
      gg[e] += __shfl_xor(gg[e], 8, 64);
    }
    if (tid == 0) {
      float* mp = reinterpret_cast<float*>(scr + SC_ME);
#pragma unroll
      for (int e = 0; e < NUM_EXPERTS; e++) mp[b * NUM_EXPERTS + e] = gg[e];
    }
  }
}

// ============ K2: ballot counts per 64-token chunk (token order) ============
__global__ __launch_bounds__(64) void k_route(
    const uint8_t* __restrict__ scr_ro, uint8_t* __restrict__ scr) {
  const int c = blockIdx.x;
  const int lane = threadIdx.x;
  const int v = scr_ro[SC_E01 + c * 64 + lane];
  const int e1 = v & 15, e2 = v >> 4;
  int mycount = 0, myce = 0;
  for (int e = 0; e < NUM_EXPERTS; e++) {
    unsigned long long m1 = __ballot(e1 == e);
    unsigned long long m2 = __ballot(e2 == e);
    if (lane == e) { mycount = __popcll(m1 | m2); myce = __popcll(m1); }
  }
  if (lane < NUM_EXPERTS) {
    reinterpret_cast<uint16_t*>(scr + SC_CNT)[lane * NBLK + c] = (uint16_t)mycount;
    reinterpret_cast<uint16_t*>(scr + SC_CE2)[lane * NBLK + c] = (uint16_t)myce;
  }
}

// ============ K3: prefix scan + l_aux (1 block) ============
__global__ __launch_bounds__(256) void k_finish(
    uint8_t* __restrict__ scr, float* __restrict__ out) {
  const uint16_t* counts = reinterpret_cast<const uint16_t*>(scr + SC_CNT);
  uint16_t* starts = reinterpret_cast<uint16_t*>(scr + SC_START);
  __shared__ int gs[NUM_EXPERTS][16];
  __shared__ int gstart[NUM_EXPERTS][17];
  __shared__ float sme[NUM_EXPERTS][17];
  __shared__ int sce[NUM_EXPERTS][17];
  const int tid = threadIdx.x;
  const int e = tid >> 4, grp = tid & 15;
  int s = 0;
  for (int c = grp * 16; c < grp * 16 + 16; c++) s += counts[e * NBLK + c];
  gs[e][grp] = s;
  // me / ce partial sums (parallel over 256 threads)
  {
    const float* mepart = reinterpret_cast<const float*>(scr + SC_ME);
    const uint16_t* ce2 = reinterpret_cast<const uint16_t*>(scr + SC_CE2);
    float ms = 0.f;
    for (int k = grp; k < GBLK; k += 16) ms += mepart[k * NUM_EXPERTS + e];
    int cs = 0;
    for (int k = grp; k < NBLK; k += 16) cs += ce2[e * NBLK + k];
    sme[e][grp] = ms; sce[e][grp] = cs;
  }
  __syncthreads();
  if (tid < NUM_EXPERTS) {
    int run = 0;
    for (int g2 = 0; g2 < 16; g2++) { gstart[tid][g2] = run; run += gs[tid][g2]; }
  }
  __syncthreads();
  int run = gstart[e][grp];
  for (int c = grp * 16; c < grp * 16 + 16; c++) {
    starts[e * NBLK + c] = (uint16_t)run;
    run += counts[e * NBLK + c];
  }
  if (tid < NUM_EXPERTS) {
    float ssum = 0.f; int ce = 0;
    for (int g2 = 0; g2 < 16; g2++) { ssum += sme[tid][g2]; ce += sce[tid][g2]; }
    float prod = (ssum * (1.0f / N_TOKENS)) * ((float)ce * (1.0f / N_TOKENS));
    prod += __shfl_xor(prod, 1, 64);
    prod += __shfl_xor(prod, 2, 64);
    prod += __shfl_xor(prod, 4, 64);
    prod += __shfl_xor(prod, 8, 64);
    if (tid == 0) out[0] = prod * (float)NUM_EXPERTS;
  }
}

// ============ K4: scatter token ids into capacity table ============
__global__ __launch_bounds__(64) void k_scatter(
    const uint8_t* __restrict__ scr, float* __restrict__ out) {
  const uint16_t* starts = reinterpret_cast<const uint16_t*>(scr + SC_START);
  const int c = blockIdx.x;
  const int lane = threadIdx.x;
  const int t = c * 64 + lane;
  const int v = scr[SC_E01 + t];
  const int e1 = v & 15, e2 = v >> 4;
  const unsigned long long below = (1ull << lane) - 1ull;
  int p1 = CAPACITY, p2 = CAPACITY;
  for (int e = 0; e < NUM_EXPERTS; e++) {
    unsigned long long m = __ballot(e1 == e) | __ballot(e2 == e);
    int r = __popcll(m & below);
    int sbase = (int)starts[e * NBLK + c];
    if (e1 == e) p1 = sbase + r;
    if (e2 == e) p2 = sbase + r;
  }
  float tf = (float)t;   // exact in fp32
  if ((unsigned)p1 < (unsigned)CAPACITY) out[IDX_OFF + e1 * CAPACITY + p1] = tf;
  if ((unsigned)p2 < (unsigned)CAPACITY) out[IDX_OFF + e2 * CAPACITY + p2] = tf;
}

// ============ K5: fill -1 in empty index slots ============
__global__ __launch_bounds__(256) void k_fill_idx(
    const uint8_t* __restrict__ scr, float* __restrict__ out) {
  const uint16_t* counts = reinterpret_cast<const uint16_t*>(scr + SC_CNT);
  const uint16_t* starts = reinterpret_cast<const uint16_t*>(scr + SC_START);
  const int i = blockIdx.x * 256 + threadIdx.x;   // 0..32767
  const int e = i >> 11;
  const int p = i & (CAPACITY - 1);
  const int tot = (int)starts[e * NBLK + NBLK - 1] + (int)counts[e * NBLK + NBLK - 1];
  if (p >= tot) out[IDX_OFF + i] = -1.0f;
}

// ============ K6 (LAST — clobbers scratch): expert_ids ============
__global__ __launch_bounds__(256) void k_eid(float* __restrict__ out) {
  const int i = blockIdx.x * 256 + threadIdx.x;   // 0..32767
  out[EID_OFF + i] = (float)(i >> 11);
}

extern "C" void kernel_launch(void* const* d_in, const int* in_sizes, int n_in,
                              void* d_out, int out_size, void* d_ws, size_t ws_size,
                              hipStream_t stream) {
  const float* x  = (const float*)d_in[0];
  const float* wg = (const float*)d_in[1];
  float* out = (float*)d_out;
  uint8_t* scr = (uint8_t*)d_out + SCR_BYTE;
  (void)d_ws; (void)ws_size;

  k_logits<<<GBLK, 256, 0, stream>>>(x, wg, out, scr);
  k_route<<<NBLK, 64, 0, stream>>>(scr, scr);
  k_finish<<<1, 256, 0, stream>>>(scr, out);
  k_scatter<<<NBLK, 64, 0, stream>>>(scr, out);
  k_fill_idx<<<128, 256, 0, stream>>>(scr, out);
  k_eid<<<128, 256, 0, stream>>>(out);
}